// Round 12
// baseline (204.899 us; speedup 1.0000x reference)
//
#include <hip/hip_runtime.h>

// MaskedAttentionLayer B=4,S=2048,E=1024,H=16,HD=64; fp32 io, bf16 MFMA.
// R18: flash_attn prefetch deepened to a 3-buffer K/V ring (stage kt+2,
// vmcnt(4)): R15's 1-tile-ahead issue->use distance (~1 body < load latency)
// stalled every tile. LDS 51.2 -> 66KB, still 2 blocks/CU (80KB budget).
// Same two-barrier skeleton, same body, same op order (bit-identical).
// qkv_gemm (R17: fused body + counted lgkm(8) overlap, ~918 TF = structure
// ceiling) and cvt_all frozen.

typedef __bf16 bf16x8 __attribute__((ext_vector_type(8)));
typedef __bf16 bf16x4 __attribute__((ext_vector_type(4)));
typedef float f32x4 __attribute__((ext_vector_type(4)));
typedef unsigned short us8 __attribute__((ext_vector_type(8)));
typedef unsigned short us4 __attribute__((ext_vector_type(4)));

#define Bb 4
#define Ss 2048
#define Ee 1024
#define Hh 16
#define HD 64

#if __has_builtin(__builtin_amdgcn_exp2f)
#define EXP2(x) __builtin_amdgcn_exp2f(x)
#else
#define EXP2(x) exp2f(x)
#endif

__device__ __forceinline__ unsigned short f2bf(float f) {
  union { float f; unsigned u; } v; v.f = f;
  unsigned u = v.u;
  u += 0x7fffu + ((u >> 16) & 1u);   // RNE
  return (unsigned short)(u >> 16);
}

__device__ __forceinline__ void gl_lds16(const void* g, void* l) {
  __builtin_amdgcn_global_load_lds((const __attribute__((address_space(1))) void*)g,
                                   (__attribute__((address_space(3))) void*)l, 16, 0, 0);
}

// asm LDS ops with compile-time byte offsets; opaque to compiler waitcnt logic.
#define DSR(d, a, o) asm volatile("ds_read_b128 %0, %1 offset:" #o : "=v"(d) : "v"(a))
#define DSW(a, d, o) asm volatile("ds_write_b64 %0, %1 offset:" #o :: "v"(a), "v"(d) : "memory")
#define LGKM0 asm volatile("s_waitcnt lgkmcnt(0)" ::: "memory"); __builtin_amdgcn_sched_barrier(0)
#define LGKM8 asm volatile("s_waitcnt lgkmcnt(8)" ::: "memory"); __builtin_amdgcn_sched_barrier(0)

// one kernel for all fp32->bf16 converts (x, Wq, Wk, Wv)
__global__ __launch_bounds__(256) void cvt_all(const float* __restrict__ x,
                                               const float* __restrict__ wq,
                                               const float* __restrict__ wk,
                                               const float* __restrict__ wv,
                                               unsigned short* __restrict__ xb,
                                               unsigned short* __restrict__ wb) {
  int i = blockIdx.x * 256 + threadIdx.x;   // float4 index, total 2883584
  const float* src; unsigned short* dst; int idx;
  if (i < 2097152)      { src = x;  dst = xb;                idx = i; }
  else if (i < 2359296) { src = wq; dst = wb;                idx = i - 2097152; }
  else if (i < 2621440) { src = wk; dst = wb + 1048576;      idx = i - 2359296; }
  else                  { src = wv; dst = wb + 2 * 1048576;  idx = i - 2621440; }
  float4 f = ((const float4*)src)[idx];
  us4 o = { f2bf(f.x), f2bf(f.y), f2bf(f.z), f2bf(f.w) };
  ((us4*)dst)[idx] = o;
}

// C[m,n] = sum_e X[m,e] W[n,e] + bias[n].  (R17 structure, verified)
// 128x128 tile, BK=64, 256 threads = 4 waves, dispersed-quadrant map
// (wave (wr,wc) owns 32x32 of each 64x64 C-quadrant). LDS 64 KiB:
// 2 x (A[128][64] + B[128][64]) bf16, XOR chunk swizzle.
// Fused body with counted-lgkm overlap. Grid (64,8,3) = 1536 blocks,
// 2 blocks/CU, 3 exact rounds.
// z=0 (Q): [b,h,s,d] scaled by 0.125*log2e.  z=1 (K): [b,h,s,d].  z=2 (V): [b,h,d,s].
__global__ __launch_bounds__(256, 2) void qkv_gemm(const unsigned short* __restrict__ xb,
                                                   const unsigned short* __restrict__ wb_all,
                                                   const float* __restrict__ bq,
                                                   const float* __restrict__ bk,
                                                   const float* __restrict__ bv,
                                                   unsigned short* __restrict__ qkv) {
  const int z = blockIdx.z;
  const unsigned short* wb = wb_all + (size_t)z * (Ee * Ee);
  const float* bias = (z == 0) ? bq : (z == 1) ? bk : bv;
  unsigned short* outb = qkv + (size_t)z * (Bb * Ss * Ee);
  const float osc = (z == 0) ? 0.180336880f : 1.0f;   // 0.125 * log2(e)

  __shared__ unsigned short SMEM[32768];   // 64 KiB: 2 x (A 8192 + B 8192 elems)

  const int t = threadIdx.x;
  const int wave = t >> 6, lane = t & 63, quad = lane >> 4, ln = lane & 15;
  const int wr = wave >> 1, wc = wave & 1;
  const int m0 = blockIdx.x * 128, n0 = blockIdx.y * 128;

  const int r32 = t >> 3;
  const int cs = ((t & 7) ^ (r32 & 7)) * 8;
  const int t8 = t * 8;
  const unsigned short* gA0 = xb + (size_t)(m0 + r32) * Ee + cs;       // A rows 0..63
  const unsigned short* gA1 = gA0 + 64 * Ee;                           // A rows 64..127
  const unsigned short* gB0 = wb + (size_t)(n0 + r32) * Ee + cs;       // B rows 0..63
  const unsigned short* gB1 = gB0 + 64 * Ee;                           // B rows 64..127

  const int swz0 = ((0 * 4 + quad) ^ (ln & 7)) * 16;
  const int swz1 = ((1 * 4 + quad) ^ (ln & 7)) * 16;
  int aA0 = (wr * 32 + ln) * 128 + swz0;
  int aA1 = (wr * 32 + ln) * 128 + swz1;
  int bA0 = 16384 + (wc * 32 + ln) * 128 + swz0;
  int bA1 = 16384 + (wc * 32 + ln) * 128 + swz1;

  f32x4 acc[2][2][2][2] = {};
  bf16x8 af0[2][2], af1[2][2], bf0[2][2], bf1[2][2];   // lo/hi A, lo/hi B

  // ---- prologue: stage tile 0 into buf0 (8 calls)
  gl_lds16(gA0,           &SMEM[t8]);
  gl_lds16(gA0 + 32 * Ee, &SMEM[t8 + 2048]);
  gl_lds16(gB0,           &SMEM[8192 + t8]);
  gl_lds16(gB0 + 32 * Ee, &SMEM[8192 + t8 + 2048]);
  gl_lds16(gB1,           &SMEM[12288 + t8]);
  gl_lds16(gB1 + 32 * Ee, &SMEM[12288 + t8 + 2048]);
  gl_lds16(gA1,           &SMEM[4096 + t8]);
  gl_lds16(gA1 + 32 * Ee, &SMEM[4096 + t8 + 2048]);

#pragma unroll 1
  for (int kt = 0; kt < 15; ++kt) {
    const int sbuf = ((kt & 1) << 14) ^ 16384;   // stage buffer (elems) for tile kt+1
    const int co = (kt + 1) * 64;                // next tile's K-column offset

    // ---- stage ALL of tile kt+1
    gl_lds16(gA0 + co,           &SMEM[sbuf + t8]);
    gl_lds16(gA0 + co + 32 * Ee, &SMEM[sbuf + t8 + 2048]);
    gl_lds16(gB0 + co,           &SMEM[sbuf + 8192 + t8]);
    gl_lds16(gB0 + co + 32 * Ee, &SMEM[sbuf + 8192 + t8 + 2048]);
    gl_lds16(gB1 + co,           &SMEM[sbuf + 12288 + t8]);
    gl_lds16(gB1 + co + 32 * Ee, &SMEM[sbuf + 12288 + t8 + 2048]);
    gl_lds16(gA1 + co,           &SMEM[sbuf + 4096 + t8]);
    gl_lds16(gA1 + co + 32 * Ee, &SMEM[sbuf + 4096 + t8 + 2048]);

    asm volatile("s_waitcnt vmcnt(8)" ::: "memory");
    asm volatile("s_barrier" ::: "memory");

    // ---- issue ALL 16 fragment reads; first 8 (af0,bf0) feed quadrant (0,0)
    DSR(af0[0][0], aA0, 0);    DSR(af0[1][0], aA0, 2048);
    DSR(af0[0][1], aA1, 0);    DSR(af0[1][1], aA1, 2048);
    DSR(bf0[0][0], bA0, 0);    DSR(bf0[1][0], bA0, 2048);
    DSR(bf0[0][1], bA1, 0);    DSR(bf0[1][1], bA1, 2048);
    DSR(af1[0][0], aA0, 8192); DSR(af1[1][0], aA0, 10240);
    DSR(af1[0][1], aA1, 8192); DSR(af1[1][1], aA1, 10240);
    DSR(bf1[0][0], bA0, 8192); DSR(bf1[1][0], bA0, 10240);
    DSR(bf1[0][1], bA1, 8192); DSR(bf1[1][1], bA1, 10240);
    LGKM8;                      // af0+bf0 ready; af1/bf1 still draining
    __builtin_amdgcn_s_setprio(1);
#pragma unroll
    for (int kk = 0; kk < 2; ++kk)
#pragma unroll
      for (int i = 0; i < 2; ++i)
#pragma unroll
        for (int j = 0; j < 2; ++j)
          acc[0][0][i][j] = __builtin_amdgcn_mfma_f32_16x16x32_bf16(af0[i][kk], bf0[j][kk], acc[0][0][i][j], 0, 0, 0);
    LGKM0;                      // all fragments ready
#pragma unroll
    for (int kk = 0; kk < 2; ++kk)
#pragma unroll
      for (int i = 0; i < 2; ++i)
#pragma unroll
        for (int j = 0; j < 2; ++j)
          acc[0][1][i][j] = __builtin_amdgcn_mfma_f32_16x16x32_bf16(af0[i][kk], bf1[j][kk], acc[0][1][i][j], 0, 0, 0);
#pragma unroll
    for (int kk = 0; kk < 2; ++kk)
#pragma unroll
      for (int i = 0; i < 2; ++i)
#pragma unroll
        for (int j = 0; j < 2; ++j)
          acc[1][0][i][j] = __builtin_amdgcn_mfma_f32_16x16x32_bf16(af1[i][kk], bf0[j][kk], acc[1][0][i][j], 0, 0, 0);
#pragma unroll
    for (int kk = 0; kk < 2; ++kk)
#pragma unroll
      for (int i = 0; i < 2; ++i)
#pragma unroll
        for (int j = 0; j < 2; ++j)
          acc[1][1][i][j] = __builtin_amdgcn_mfma_f32_16x16x32_bf16(af1[i][kk], bf1[j][kk], acc[1][1][i][j], 0, 0, 0);
    __builtin_amdgcn_s_setprio(0);
    __builtin_amdgcn_sched_barrier(0);
    asm volatile("s_barrier" ::: "memory");      // reads done before next stage

    aA0 ^= 32768; aA1 ^= 32768; bA0 ^= 32768; bA1 ^= 32768;
  }

  // ---- peeled tile 15: only place vmcnt drains to 0 (bases now at buf1)
  {
    asm volatile("s_waitcnt vmcnt(0)" ::: "memory");
    asm volatile("s_barrier" ::: "memory");
    DSR(af0[0][0], aA0, 0);    DSR(af0[1][0], aA0, 2048);
    DSR(af0[0][1], aA1, 0);    DSR(af0[1][1], aA1, 2048);
    DSR(bf0[0][0], bA0, 0);    DSR(bf0[1][0], bA0, 2048);
    DSR(bf0[0][1], bA1, 0);    DSR(bf0[1][1], bA1, 2048);
    DSR(af1[0][0], aA0, 8192); DSR(af1[1][0], aA0, 10240);
    DSR(af1[0][1], aA1, 8192); DSR(af1[1][1], aA1, 10240);
    DSR(bf1[0][0], bA0, 8192); DSR(bf1[1][0], bA0, 10240);
    DSR(bf1[0][1], bA1, 8192); DSR(bf1[1][1], bA1, 10240);
    LGKM8;
#pragma unroll
    for (int kk = 0; kk < 2; ++kk)
#pragma unroll
      for (int i = 0; i < 2; ++i)
#pragma unroll
        for (int j = 0; j < 2; ++j)
          acc[0][0][i][j] = __builtin_amdgcn_mfma_f32_16x16x32_bf16(af0[i][kk], bf0[j][kk], acc[0][0][i][j], 0, 0, 0);
    LGKM0;
#pragma unroll
    for (int kk = 0; kk < 2; ++kk)
#pragma unroll
      for (int i = 0; i < 2; ++i)
#pragma unroll
        for (int j = 0; j < 2; ++j)
          acc[0][1][i][j] = __builtin_amdgcn_mfma_f32_16x16x32_bf16(af0[i][kk], bf1[j][kk], acc[0][1][i][j], 0, 0, 0);
#pragma unroll
    for (int kk = 0; kk < 2; ++kk)
#pragma unroll
      for (int i = 0; i < 2; ++i)
#pragma unroll
        for (int j = 0; j < 2; ++j)
          acc[1][0][i][j] = __builtin_amdgcn_mfma_f32_16x16x32_bf16(af1[i][kk], bf0[j][kk], acc[1][0][i][j], 0, 0, 0);
#pragma unroll
    for (int kk = 0; kk < 2; ++kk)
#pragma unroll
      for (int i = 0; i < 2; ++i)
#pragma unroll
        for (int j = 0; j < 2; ++j)
          acc[1][1][i][j] = __builtin_amdgcn_mfma_f32_16x16x32_bf16(af1[i][kk], bf1[j][kk], acc[1][1][i][j], 0, 0, 0);
    __builtin_amdgcn_sched_barrier(0);
  }

  // ---- epilogue
  float biasj[2][2];
#pragma unroll
  for (int qb = 0; qb < 2; ++qb)
#pragma unroll
    for (int j = 0; j < 2; ++j)
      biasj[qb][j] = bias[n0 + qb * 64 + wc * 32 + j * 16 + ln];

  if (z != 2) {
#pragma unroll
    for (int qa = 0; qa < 2; ++qa)
#pragma unroll
      for (int qb = 0; qb < 2; ++qb)
#pragma unroll
        for (int i = 0; i < 2; ++i)
#pragma unroll
          for (int j = 0; j < 2; ++j)
#pragma unroll
            for (int r = 0; r < 4; ++r) {
              int m = m0 + qa * 64 + wr * 32 + i * 16 + quad * 4 + r;
              int n = n0 + qb * 64 + wc * 32 + j * 16 + ln;
              int b_ = m >> 11, s = m & 2047;
              int h = n >> 6, d = n & 63;
              outb[(((size_t)b_ * Hh + h) * Ss + s) * HD + d] =
                  f2bf((acc[qa][qb][i][j][r] + biasj[qb][j]) * osc);
            }
  } else {
    // V: transpose to [b,h,d,s] through LDS (128x128 fits in one pass)
    __syncthreads();
#pragma unroll
    for (int qa = 0; qa < 2; ++qa)
#pragma unroll
      for (int qb = 0; qb < 2; ++qb)
#pragma unroll
        for (int i = 0; i < 2; ++i)
#pragma unroll
          for (int j = 0; j < 2; ++j)
#pragma unroll
            for (int r = 0; r < 4; ++r) {
              int nc = qb * 64 + wc * 32 + j * 16 + ln;
              int mr = qa * 64 + wr * 32 + i * 16 + quad * 4 + r;
              SMEM[nc * 136 + mr] = f2bf(acc[qa][qb][i][j][r] + biasj[qb][j]);
            }
    __syncthreads();
    int nr = t >> 1, mh = t & 1;
    int n = n0 + nr, h = n >> 6, d = n & 63;
    int b_ = m0 >> 11;
    int s0 = (m0 & 2047) + mh * 64;
#pragma unroll
    for (int q = 0; q < 8; ++q) {
      us8 vdat = *(const us8*)&SMEM[nr * 136 + mh * 64 + q * 8];
      *(us8*)&outb[(((size_t)b_ * Hh + h) * HD + d) * Ss + s0 + q * 8] = vdat;
    }
  }
}

// Flash attention, causal, S^T = K Q^T, max-free exp2 softmax.
// R18: grid 512 (64 bh x 8 p), 512 thr / 8 waves, 2 blocks/CU. Block p owns
// q-tiles {15-p, p}; wave w owns 16-row strip w*16 of each. KVBLK=64,
// THREE-buffer K/V ring: per tile {stage(kt+2); vmcnt(4); bar; asm-LDS
// compute; bar}; peeled last two tiles drain vmcnt(2)/(0). Two-barrier
// skeleton and body identical to R15 (bit-identical outputs).
// LDS bytes: Ks buf b @ b*8192 (0..24575); Vt buf b @ 24576+b*8192
// (24576..49151); Ps @ 49152..67583. 67584 B total (2 blocks/CU, <=80KB).
__global__ __launch_bounds__(512, 2) void flash_attn(const unsigned short* __restrict__ qkv,
                                                     float* __restrict__ out) {
  const int id = blockIdx.x;
  const int bh = id & 63;
  const int p = id >> 6;            // 0..7
  const int b_ = bh >> 4, h = bh & 15;

  const unsigned short* qb  = qkv + (size_t)bh * (Ss * HD);
  const unsigned short* kb  = qkv + (size_t)(64 + bh) * (Ss * HD);
  const unsigned short* vtb = qkv + (size_t)(128 + bh) * (Ss * HD);  // [d][s]

  __shared__ __bf16 LDS[33792];        // 67584 B (see header comment)

  const int t = threadIdx.x;
  const int wave = t >> 6, lane = t & 63, quad = lane >> 4, ln = lane & 15;
  const int uw = wave >> 2;            // 64-row subtile half within each q-tile

  const int r6 = t >> 3;
  const int cstage = ((t & 7) ^ (r6 & 7)) * 8;
  const int t8 = t * 8;

  const int qts[2] = { 15 - p, p };    // big q-tile first; small reuses staging
  const int KTB = 2 * qts[0] + 2;      // 64-col K/V tiles (block-uniform, >= 18)
  const int su0 = 2 * qts[0] + uw;
  const int su1 = 2 * qts[1] + uw;
  const int qrow0 = qts[0] * 128 + wave * 16 + ln;
  const int qrow1 = qts[1] * 128 + wave * 16 + ln;

  // lane-constant low byte addrs within a K buffer; V = K + 24576 (const offset)
  const int ka0l = ln * 128 + ((quad ^ (ln & 7)) * 16);
  const int ka1l = ln * 128 + (((4 + quad) ^ (ln & 7)) * 16);
  const int pw = 49152 + (wave * 16 + ln) * 144 + quad * 8;
  const int pr = 49152 + (wave * 16 + ln) * 144 + quad * 16;

  bf16x8 qf[2][2];                     // [qt][ks] — loaded BEFORE any gl_lds16
#pragma unroll
  for (int qt = 0; qt < 2; ++qt)
#pragma unroll
    for (int ks = 0; ks < 2; ++ks)
      qf[qt][ks] = *(const bf16x8*)(qb + (size_t)(qts[qt] * 128 + wave * 16 + ln) * HD +
                                    ks * 32 + quad * 8);

  bf16x8 onef;
#pragma unroll
  for (int j = 0; j < 8; ++j) onef[j] = (__bf16)1.0f;

  f32x4 o[2][4] = {};                  // [qt][g]
  f32x4 l4[2] = {};                    // [qt]

  // compute body for one 64-col K/V tile; kaA/kaB = buffer-adjusted byte bases.
  // NO barriers inside; wave-uniform guards only.
  auto body = [&](int kt, int kaA, int kaB) {
    if (kt > su0) return;              // fully masked for this wave
    const bool a1 = (kt <= su1);
    const int k0 = kt * 64;
    f32x4 s0[4] = {}, s1[4] = {};
    bf16x8 kf[2][2];

    DSR(kf[0][0], kaA, 0);    DSR(kf[1][0], kaA, 2048);
    DSR(kf[0][1], kaB, 0);    DSR(kf[1][1], kaB, 2048);
    LGKM0;
#pragma unroll
    for (int ks = 0; ks < 2; ++ks) {
      s0[0] = __builtin_amdgcn_mfma_f32_16x16x32_bf16(kf[0][ks], qf[0][ks], s0[0], 0, 0, 0);
      s0[1] = __builtin_amdgcn_mfma_f32_16x16x32_bf16(kf[1][ks], qf[0][ks], s0[1], 0, 0, 0);
    }
    if (a1)
#pragma unroll
      for (int ks = 0; ks < 2; ++ks) {
        s1[0] = __builtin_amdgcn_mfma_f32_16x16x32_bf16(kf[0][ks], qf[1][ks], s1[0], 0, 0, 0);
        s1[1] = __builtin_amdgcn_mfma_f32_16x16x32_bf16(kf[1][ks], qf[1][ks], s1[1], 0, 0, 0);
      }
    DSR(kf[0][0], kaA, 4096); DSR(kf[1][0], kaA, 6144);
    DSR(kf[0][1], kaB, 4096); DSR(kf[1][1], kaB, 6144);
    LGKM0;
#pragma unroll
    for (int ks = 0; ks < 2; ++ks) {
      s0[2] = __builtin_amdgcn_mfma_f32_16x16x32_bf16(kf[0][ks], qf[0][ks], s0[2], 0, 0, 0);
      s0[3] = __builtin_amdgcn_mfma_f32_16x16x32_bf16(kf[1][ks], qf[0][ks], s0[3], 0, 0, 0);
    }
    if (a1)
#pragma unroll
      for (int ks = 0; ks < 2; ++ks) {
        s1[2] = __builtin_amdgcn_mfma_f32_16x16x32_bf16(kf[0][ks], qf[1][ks], s1[2], 0, 0, 0);
        s1[3] = __builtin_amdgcn_mfma_f32_16x16x32_bf16(kf[1][ks], qf[1][ks], s1[3], 0, 0, 0);
      }

    if (kt == su0) {
#pragma unroll
      for (int g = 0; g < 4; ++g)
#pragma unroll
        for (int r = 0; r < 4; ++r) {
          int kcol = k0 + g * 16 + quad * 4 + r;
          if (kcol > qrow0) s0[g][r] = -__builtin_inff();
        }
    }
    {
      bf16x4 pk;
      pk = bf16x4{ (__bf16)EXP2(s0[0][0]), (__bf16)EXP2(s0[0][1]), (__bf16)EXP2(s0[0][2]), (__bf16)EXP2(s0[0][3]) };
      DSW(pw, pk, 0);
      pk = bf16x4{ (__bf16)EXP2(s0[1][0]), (__bf16)EXP2(s0[1][1]), (__bf16)EXP2(s0[1][2]), (__bf16)EXP2(s0[1][3]) };
      DSW(pw, pk, 32);
      pk = bf16x4{ (__bf16)EXP2(s0[2][0]), (__bf16)EXP2(s0[2][1]), (__bf16)EXP2(s0[2][2]), (__bf16)EXP2(s0[2][3]) };
      DSW(pw, pk, 64);
      pk = bf16x4{ (__bf16)EXP2(s0[3][0]), (__bf16)EXP2(s0[3][1]), (__bf16)EXP2(s0[3][2]), (__bf16)EXP2(s0[3][3]) };
      DSW(pw, pk, 96);
    }
    bf16x8 pf0[2], pf1[2];
    DSR(pf0[0], pr, 0); DSR(pf0[1], pr, 64);
    LGKM0;                              // pf0 in regs; Ps now free for reuse

    if (a1) {                           // softmax small q-tile (overwrites Ps)
      if (kt == su1) {
#pragma unroll
        for (int g = 0; g < 4; ++g)
#pragma unroll
          for (int r = 0; r < 4; ++r) {
            int kcol = k0 + g * 16 + quad * 4 + r;
            if (kcol > qrow1) s1[g][r] = -__builtin_inff();
          }
      }
      bf16x4 pk;
      pk = bf16x4{ (__bf16)EXP2(s1[0][0]), (__bf16)EXP2(s1[0][1]), (__bf16)EXP2(s1[0][2]), (__bf16)EXP2(s1[0][3]) };
      DSW(pw, pk, 0);
      pk = bf16x4{ (__bf16)EXP2(s1[1][0]), (__bf16)EXP2(s1[1][1]), (__bf16)EXP2(s1[1][2]), (__bf16)EXP2(s1[1][3]) };
      DSW(pw, pk, 32);
      pk = bf16x4{ (__bf16)EXP2(s1[2][0]), (__bf16)EXP2(s1[2][1]), (__bf16)EXP2(s1[2][2]), (__bf16)EXP2(s1[2][3]) };
      DSW(pw, pk, 64);
      pk = bf16x4{ (__bf16)EXP2(s1[3][0]), (__bf16)EXP2(s1[3][1]), (__bf16)EXP2(s1[3][2]), (__bf16)EXP2(s1[3][3]) };
      DSW(pw, pk, 96);
      DSR(pf1[0], pr, 0); DSR(pf1[1], pr, 64);
      LGKM0;
    }

    l4[0] = __builtin_amdgcn_mfma_f32_16x16x32_bf16(pf0[0], onef, l4[0], 0, 0, 0);
    l4[0] = __builtin_amdgcn_mfma_f32_16x16x32_bf16(pf0[1], onef, l4[0], 0, 0, 0);
    if (a1) {
      l4[1] = __builtin_amdgcn_mfma_f32_16x16x32_bf16(pf1[0], onef, l4[1], 0, 0, 0);
      l4[1] = __builtin_amdgcn_mfma_f32_16x16x32_bf16(pf1[1], onef, l4[1], 0, 0, 0);
    }

    // O += P V ; V buffer = K buffer + 24576 B (ring-constant offset)
    DSR(kf[0][0], kaA, 24576); DSR(kf[1][0], kaA, 26624);
    DSR(kf[0][1], kaB, 24576); DSR(kf[1][1], kaB, 26624);
    LGKM0;
#pragma unroll
    for (int ks = 0; ks < 2; ++ks) {
      o[0][0] = __builtin_amdgcn_mfma_f32_16x16x32_bf16(pf0[ks], kf[0][ks], o[0][0], 0, 0, 0);
      o[0][1] = __builtin_amdgcn_mfma_f32_16x16x32_bf16(pf0[ks], kf[1][ks], o[0][1], 0, 0, 0);
    }
    if (a1)
#pragma unroll
      for (int ks = 0; ks < 2; ++ks) {
        o[1][0] = __builtin_amdgcn_mfma_f32_16x16x32_bf16(pf1[ks], kf[0][ks], o[1][0], 0, 0, 0);
        o[1][1] = __builtin_amdgcn_mfma_f32_16x16x32_bf16(pf1[ks], kf[1][ks], o[1][1], 0, 0, 0);
      }
    DSR(kf[0][0], kaA, 28672); DSR(kf[1][0], kaA, 30720);
    DSR(kf[0][1], kaB, 28672); DSR(kf[1][1], kaB, 30720);
    LGKM0;
#pragma unroll
    for (int ks = 0; ks < 2; ++ks) {
      o[0][2] = __builtin_amdgcn_mfma_f32_16x16x32_bf16(pf0[ks], kf[0][ks], o[0][2], 0, 0, 0);
      o[0][3] = __builtin_amdgcn_mfma_f32_16x16x32_bf16(pf0[ks], kf[1][ks], o[0][3], 0, 0, 0);
    }
    if (a1)
#pragma unroll
      for (int ks = 0; ks < 2; ++ks) {
        o[1][2] = __builtin_amdgcn_mfma_f32_16x16x32_bf16(pf1[ks], kf[0][ks], o[1][2], 0, 0, 0);
        o[1][3] = __builtin_amdgcn_mfma_f32_16x16x32_bf16(pf1[ks], kf[1][ks], o[1][3], 0, 0, 0);
      }
  };

  // ---- prologue: stage tiles 0 and 1 -> bufs 0,1 (K then V per tile; vmcnt order)
  gl_lds16(kb + r6 * HD + cstage,             &LDS[t8]);
  gl_lds16(vtb + r6 * Ss + cstage,            &LDS[12288 + t8]);
  gl_lds16(kb + 64 * HD + r6 * HD + cstage,   &LDS[4096 + t8]);
  gl_lds16(vtb + 64 + r6 * Ss + cstage,       &LDS[12288 + 4096 + t8]);

  int cOff = 0;                        // compute-buffer byte offset: 0,8192,16384 ring
  int sOff = 16384;                    // stage-buffer byte offset for tile kt+2
#pragma unroll 1
  for (int kt = 0; kt < KTB - 2; ++kt) {
    const int sE = sOff >> 1;          // stage buffer elem offset
    gl_lds16(kb + (size_t)(kt + 2) * (64 * HD) + r6 * HD + cstage, &LDS[sE + t8]);
    gl_lds16(vtb + (kt + 2) * 64 + r6 * Ss + cstage,               &LDS[12288 + sE + t8]);
    asm volatile("s_waitcnt vmcnt(4)" ::: "memory");   // tile kt's K,V arrived
    asm volatile("s_barrier" ::: "memory");
    body(kt, ka0l + cOff, ka1l + cOff);
    asm volatile("s_barrier" ::: "memory");            // reads done before next stage
    cOff = (cOff == 16384) ? 0 : cOff + 8192;
    sOff = (sOff == 16384) ? 0 : sOff + 8192;
  }
  // peeled tile KTB-2
  asm volatile("s_waitcnt vmcnt(2)" ::: "memory");
  asm volatile("s_barrier" ::: "memory");
  body(KTB - 2, ka0l + cOff, ka1l + cOff);
  asm volatile("s_barrier" ::: "memory");
  cOff = (cOff == 16384) ? 0 : cOff + 8192;
  // peeled tile KTB-1: only vmcnt(0) drain
  asm volatile("s_waitcnt vmcnt(0)" ::: "memory");
  asm volatile("s_barrier" ::: "memory");
  body(KTB - 1, ka0l + cOff, ka1l + cOff);

  // epilogue: both q-tiles
#pragma unroll
  for (int qt = 0; qt < 2; ++qt) {
    float linv[4];
#pragma unroll
    for (int r = 0; r < 4; ++r) linv[r] = 1.0f / l4[qt][r];
#pragma unroll
    for (int g = 0; g < 4; ++g)
#pragma unroll
      for (int r = 0; r < 4; ++r) {
        int orow = qts[qt] * 128 + wave * 16 + quad * 4 + r;
        out[((size_t)b_ * Ss + orow) * Ee + h * HD + g * 16 + ln] = o[qt][g][r] * linv[r];
      }
  }
}

extern "C" void kernel_launch(void* const* d_in, const int* in_sizes, int n_in,
                              void* d_out, int out_size, void* d_ws, size_t ws_size,
                              hipStream_t stream) {
  const float* x  = (const float*)d_in[0];
  const float* Wq = (const float*)d_in[1];
  const float* bq = (const float*)d_in[2];
  const float* Wk = (const float*)d_in[3];
  const float* bk = (const float*)d_in[4];
  const float* Wv = (const float*)d_in[5];
  const float* bv = (const float*)d_in[6];
  float* out = (float*)d_out;

  unsigned short* ws  = (unsigned short*)d_ws;
  unsigned short* xb  = ws;                                   // 8388608
  unsigned short* wb  = ws + 8388608;                         // 3 * 1048576
  unsigned short* qkv = ws + 8388608 + 3 * 1048576;           // 3 * 8388608

  cvt_all<<<11264, 256, 0, stream>>>(x, Wq, Wk, Wv, xb, wb);
  qkv_gemm<<<dim3(64, 8, 3), 256, 0, stream>>>(xb, wb, bq, bk, bv, qkv);
  flash_attn<<<512, 512, 0, stream>>>(qkv, out);
}

// Round 13
// 196.781 us; speedup vs baseline: 1.0413x; 1.0413x over previous
//
#include <hip/hip_runtime.h>

// MaskedAttentionLayer B=4,S=2048,E=1024,H=16,HD=64; fp32 io, bf16 MFMA.
// R19: REVERT to the R17 build (best verified, 193.9us). R18's 3-buffer
// ring regressed flash by ~11us (deeper prefetch refuted: stall is the
// serial in-body chain, not load arrival; ring's runtime bases defeated
// offset folding). qkv_gemm: R17 fused body + counted lgkm(8) overlap
// (~918 TF = structure ceiling). flash_attn: R15 two-barrier counted-vmcnt
// KVBLK=64 double-buffer. cvt_all at BW floor.

typedef __bf16 bf16x8 __attribute__((ext_vector_type(8)));
typedef __bf16 bf16x4 __attribute__((ext_vector_type(4)));
typedef float f32x4 __attribute__((ext_vector_type(4)));
typedef unsigned short us8 __attribute__((ext_vector_type(8)));
typedef unsigned short us4 __attribute__((ext_vector_type(4)));

#define Bb 4
#define Ss 2048
#define Ee 1024
#define Hh 16
#define HD 64

#if __has_builtin(__builtin_amdgcn_exp2f)
#define EXP2(x) __builtin_amdgcn_exp2f(x)
#else
#define EXP2(x) exp2f(x)
#endif

__device__ __forceinline__ unsigned short f2bf(float f) {
  union { float f; unsigned u; } v; v.f = f;
  unsigned u = v.u;
  u += 0x7fffu + ((u >> 16) & 1u);   // RNE
  return (unsigned short)(u >> 16);
}

__device__ __forceinline__ void gl_lds16(const void* g, void* l) {
  __builtin_amdgcn_global_load_lds((const __attribute__((address_space(1))) void*)g,
                                   (__attribute__((address_space(3))) void*)l, 16, 0, 0);
}

// asm LDS ops with compile-time byte offsets; opaque to compiler waitcnt logic.
#define DSR(d, a, o) asm volatile("ds_read_b128 %0, %1 offset:" #o : "=v"(d) : "v"(a))
#define DSW(a, d, o) asm volatile("ds_write_b64 %0, %1 offset:" #o :: "v"(a), "v"(d) : "memory")
#define LGKM0 asm volatile("s_waitcnt lgkmcnt(0)" ::: "memory"); __builtin_amdgcn_sched_barrier(0)
#define LGKM8 asm volatile("s_waitcnt lgkmcnt(8)" ::: "memory"); __builtin_amdgcn_sched_barrier(0)

// one kernel for all fp32->bf16 converts (x, Wq, Wk, Wv)
__global__ __launch_bounds__(256) void cvt_all(const float* __restrict__ x,
                                               const float* __restrict__ wq,
                                               const float* __restrict__ wk,
                                               const float* __restrict__ wv,
                                               unsigned short* __restrict__ xb,
                                               unsigned short* __restrict__ wb) {
  int i = blockIdx.x * 256 + threadIdx.x;   // float4 index, total 2883584
  const float* src; unsigned short* dst; int idx;
  if (i < 2097152)      { src = x;  dst = xb;                idx = i; }
  else if (i < 2359296) { src = wq; dst = wb;                idx = i - 2097152; }
  else if (i < 2621440) { src = wk; dst = wb + 1048576;      idx = i - 2359296; }
  else                  { src = wv; dst = wb + 2 * 1048576;  idx = i - 2621440; }
  float4 f = ((const float4*)src)[idx];
  us4 o = { f2bf(f.x), f2bf(f.y), f2bf(f.z), f2bf(f.w) };
  ((us4*)dst)[idx] = o;
}

// C[m,n] = sum_e X[m,e] W[n,e] + bias[n].
// 128x128 tile, BK=64, 256 threads = 4 waves, dispersed-quadrant map
// (wave (wr,wc) owns 32x32 of each 64x64 C-quadrant). LDS 64 KiB:
// 2 x (A[128][64] + B[128][64]) bf16, XOR chunk swizzle.
// R17: fused body with counted-lgkm overlap. Grid (64,8,3) =
// 1536 blocks, 2 blocks/CU, 3 exact rounds.
// z=0 (Q): [b,h,s,d] scaled by 0.125*log2e.  z=1 (K): [b,h,s,d].  z=2 (V): [b,h,d,s].
__global__ __launch_bounds__(256, 2) void qkv_gemm(const unsigned short* __restrict__ xb,
                                                   const unsigned short* __restrict__ wb_all,
                                                   const float* __restrict__ bq,
                                                   const float* __restrict__ bk,
                                                   const float* __restrict__ bv,
                                                   unsigned short* __restrict__ qkv) {
  const int z = blockIdx.z;
  const unsigned short* wb = wb_all + (size_t)z * (Ee * Ee);
  const float* bias = (z == 0) ? bq : (z == 1) ? bk : bv;
  unsigned short* outb = qkv + (size_t)z * (Bb * Ss * Ee);
  const float osc = (z == 0) ? 0.180336880f : 1.0f;   // 0.125 * log2(e)

  __shared__ unsigned short SMEM[32768];   // 64 KiB: 2 x (A 8192 + B 8192 elems)

  const int t = threadIdx.x;
  const int wave = t >> 6, lane = t & 63, quad = lane >> 4, ln = lane & 15;
  const int wr = wave >> 1, wc = wave & 1;
  const int m0 = blockIdx.x * 128, n0 = blockIdx.y * 128;

  const int r32 = t >> 3;
  const int cs = ((t & 7) ^ (r32 & 7)) * 8;
  const int t8 = t * 8;
  const unsigned short* gA0 = xb + (size_t)(m0 + r32) * Ee + cs;       // A rows 0..63
  const unsigned short* gA1 = gA0 + 64 * Ee;                           // A rows 64..127
  const unsigned short* gB0 = wb + (size_t)(n0 + r32) * Ee + cs;       // B rows 0..63
  const unsigned short* gB1 = gB0 + 64 * Ee;                           // B rows 64..127

  const int swz0 = ((0 * 4 + quad) ^ (ln & 7)) * 16;
  const int swz1 = ((1 * 4 + quad) ^ (ln & 7)) * 16;
  int aA0 = (wr * 32 + ln) * 128 + swz0;
  int aA1 = (wr * 32 + ln) * 128 + swz1;
  int bA0 = 16384 + (wc * 32 + ln) * 128 + swz0;
  int bA1 = 16384 + (wc * 32 + ln) * 128 + swz1;

  f32x4 acc[2][2][2][2] = {};
  bf16x8 af0[2][2], af1[2][2], bf0[2][2], bf1[2][2];   // lo/hi A, lo/hi B

  // ---- prologue: stage tile 0 into buf0 (8 calls)
  gl_lds16(gA0,           &SMEM[t8]);
  gl_lds16(gA0 + 32 * Ee, &SMEM[t8 + 2048]);
  gl_lds16(gB0,           &SMEM[8192 + t8]);
  gl_lds16(gB0 + 32 * Ee, &SMEM[8192 + t8 + 2048]);
  gl_lds16(gB1,           &SMEM[12288 + t8]);
  gl_lds16(gB1 + 32 * Ee, &SMEM[12288 + t8 + 2048]);
  gl_lds16(gA1,           &SMEM[4096 + t8]);
  gl_lds16(gA1 + 32 * Ee, &SMEM[4096 + t8 + 2048]);

#pragma unroll 1
  for (int kt = 0; kt < 15; ++kt) {
    const int sbuf = ((kt & 1) << 14) ^ 16384;   // stage buffer (elems) for tile kt+1
    const int co = (kt + 1) * 64;                // next tile's K-column offset

    // ---- stage ALL of tile kt+1 (prev iteration's trailing barrier ensures
    // every wave finished reading this buffer)
    gl_lds16(gA0 + co,           &SMEM[sbuf + t8]);
    gl_lds16(gA0 + co + 32 * Ee, &SMEM[sbuf + t8 + 2048]);
    gl_lds16(gB0 + co,           &SMEM[sbuf + 8192 + t8]);
    gl_lds16(gB0 + co + 32 * Ee, &SMEM[sbuf + 8192 + t8 + 2048]);
    gl_lds16(gB1 + co,           &SMEM[sbuf + 12288 + t8]);
    gl_lds16(gB1 + co + 32 * Ee, &SMEM[sbuf + 12288 + t8 + 2048]);
    gl_lds16(gA1 + co,           &SMEM[sbuf + 4096 + t8]);
    gl_lds16(gA1 + co + 32 * Ee, &SMEM[sbuf + 4096 + t8 + 2048]);

    // tile kt's 8 loads arrived; kt+1's 8 stay in flight under the compute
    asm volatile("s_waitcnt vmcnt(8)" ::: "memory");
    asm volatile("s_barrier" ::: "memory");

    // ---- issue ALL 16 fragment reads; first 8 (af0,bf0) feed quadrant (0,0)
    DSR(af0[0][0], aA0, 0);    DSR(af0[1][0], aA0, 2048);
    DSR(af0[0][1], aA1, 0);    DSR(af0[1][1], aA1, 2048);
    DSR(bf0[0][0], bA0, 0);    DSR(bf0[1][0], bA0, 2048);
    DSR(bf0[0][1], bA1, 0);    DSR(bf0[1][1], bA1, 2048);
    DSR(af1[0][0], aA0, 8192); DSR(af1[1][0], aA0, 10240);
    DSR(af1[0][1], aA1, 8192); DSR(af1[1][1], aA1, 10240);
    DSR(bf1[0][0], bA0, 8192); DSR(bf1[1][0], bA0, 10240);
    DSR(bf1[0][1], bA1, 8192); DSR(bf1[1][1], bA1, 10240);
    LGKM8;                      // af0+bf0 ready; af1/bf1 still draining
    __builtin_amdgcn_s_setprio(1);
    // quadrant (0,0): af-lo x bf0 — overlaps the last 8 ds_reads
#pragma unroll
    for (int kk = 0; kk < 2; ++kk)
#pragma unroll
      for (int i = 0; i < 2; ++i)
#pragma unroll
        for (int j = 0; j < 2; ++j)
          acc[0][0][i][j] = __builtin_amdgcn_mfma_f32_16x16x32_bf16(af0[i][kk], bf0[j][kk], acc[0][0][i][j], 0, 0, 0);
    LGKM0;                      // all fragments ready
    // quadrant (0,1): af-lo x bf1
#pragma unroll
    for (int kk = 0; kk < 2; ++kk)
#pragma unroll
      for (int i = 0; i < 2; ++i)
#pragma unroll
        for (int j = 0; j < 2; ++j)
          acc[0][1][i][j] = __builtin_amdgcn_mfma_f32_16x16x32_bf16(af0[i][kk], bf1[j][kk], acc[0][1][i][j], 0, 0, 0);
    // quadrant (1,0): af-hi x bf0
#pragma unroll
    for (int kk = 0; kk < 2; ++kk)
#pragma unroll
      for (int i = 0; i < 2; ++i)
#pragma unroll
        for (int j = 0; j < 2; ++j)
          acc[1][0][i][j] = __builtin_amdgcn_mfma_f32_16x16x32_bf16(af1[i][kk], bf0[j][kk], acc[1][0][i][j], 0, 0, 0);
    // quadrant (1,1): af-hi x bf1
#pragma unroll
    for (int kk = 0; kk < 2; ++kk)
#pragma unroll
      for (int i = 0; i < 2; ++i)
#pragma unroll
        for (int j = 0; j < 2; ++j)
          acc[1][1][i][j] = __builtin_amdgcn_mfma_f32_16x16x32_bf16(af1[i][kk], bf1[j][kk], acc[1][1][i][j], 0, 0, 0);
    __builtin_amdgcn_s_setprio(0);
    __builtin_amdgcn_sched_barrier(0);
    asm volatile("s_barrier" ::: "memory");      // reads done before next stage

    aA0 ^= 32768; aA1 ^= 32768; bA0 ^= 32768; bA1 ^= 32768;
  }

  // ---- peeled tile 15: only place vmcnt drains to 0 (bases now at buf1)
  {
    asm volatile("s_waitcnt vmcnt(0)" ::: "memory");
    asm volatile("s_barrier" ::: "memory");
    DSR(af0[0][0], aA0, 0);    DSR(af0[1][0], aA0, 2048);
    DSR(af0[0][1], aA1, 0);    DSR(af0[1][1], aA1, 2048);
    DSR(bf0[0][0], bA0, 0);    DSR(bf0[1][0], bA0, 2048);
    DSR(bf0[0][1], bA1, 0);    DSR(bf0[1][1], bA1, 2048);
    DSR(af1[0][0], aA0, 8192); DSR(af1[1][0], aA0, 10240);
    DSR(af1[0][1], aA1, 8192); DSR(af1[1][1], aA1, 10240);
    DSR(bf1[0][0], bA0, 8192); DSR(bf1[1][0], bA0, 10240);
    DSR(bf1[0][1], bA1, 8192); DSR(bf1[1][1], bA1, 10240);
    LGKM8;
#pragma unroll
    for (int kk = 0; kk < 2; ++kk)
#pragma unroll
      for (int i = 0; i < 2; ++i)
#pragma unroll
        for (int j = 0; j < 2; ++j)
          acc[0][0][i][j] = __builtin_amdgcn_mfma_f32_16x16x32_bf16(af0[i][kk], bf0[j][kk], acc[0][0][i][j], 0, 0, 0);
    LGKM0;
#pragma unroll
    for (int kk = 0; kk < 2; ++kk)
#pragma unroll
      for (int i = 0; i < 2; ++i)
#pragma unroll
        for (int j = 0; j < 2; ++j)
          acc[0][1][i][j] = __builtin_amdgcn_mfma_f32_16x16x32_bf16(af0[i][kk], bf1[j][kk], acc[0][1][i][j], 0, 0, 0);
#pragma unroll
    for (int kk = 0; kk < 2; ++kk)
#pragma unroll
      for (int i = 0; i < 2; ++i)
#pragma unroll
        for (int j = 0; j < 2; ++j)
          acc[1][0][i][j] = __builtin_amdgcn_mfma_f32_16x16x32_bf16(af1[i][kk], bf0[j][kk], acc[1][0][i][j], 0, 0, 0);
#pragma unroll
    for (int kk = 0; kk < 2; ++kk)
#pragma unroll
      for (int i = 0; i < 2; ++i)
#pragma unroll
        for (int j = 0; j < 2; ++j)
          acc[1][1][i][j] = __builtin_amdgcn_mfma_f32_16x16x32_bf16(af1[i][kk], bf1[j][kk], acc[1][1][i][j], 0, 0, 0);
    __builtin_amdgcn_sched_barrier(0);
  }

  // ---- epilogue
  float biasj[2][2];
#pragma unroll
  for (int qb = 0; qb < 2; ++qb)
#pragma unroll
    for (int j = 0; j < 2; ++j)
      biasj[qb][j] = bias[n0 + qb * 64 + wc * 32 + j * 16 + ln];

  if (z != 2) {
#pragma unroll
    for (int qa = 0; qa < 2; ++qa)
#pragma unroll
      for (int qb = 0; qb < 2; ++qb)
#pragma unroll
        for (int i = 0; i < 2; ++i)
#pragma unroll
          for (int j = 0; j < 2; ++j)
#pragma unroll
            for (int r = 0; r < 4; ++r) {
              int m = m0 + qa * 64 + wr * 32 + i * 16 + quad * 4 + r;
              int n = n0 + qb * 64 + wc * 32 + j * 16 + ln;
              int b_ = m >> 11, s = m & 2047;
              int h = n >> 6, d = n & 63;
              outb[(((size_t)b_ * Hh + h) * Ss + s) * HD + d] =
                  f2bf((acc[qa][qb][i][j][r] + biasj[qb][j]) * osc);
            }
  } else {
    // V: transpose to [b,h,d,s] through LDS (128x128 fits in one pass)
    __syncthreads();
#pragma unroll
    for (int qa = 0; qa < 2; ++qa)
#pragma unroll
      for (int qb = 0; qb < 2; ++qb)
#pragma unroll
        for (int i = 0; i < 2; ++i)
#pragma unroll
          for (int j = 0; j < 2; ++j)
#pragma unroll
            for (int r = 0; r < 4; ++r) {
              int nc = qb * 64 + wc * 32 + j * 16 + ln;
              int mr = qa * 64 + wr * 32 + i * 16 + quad * 4 + r;
              SMEM[nc * 136 + mr] = f2bf(acc[qa][qb][i][j][r] + biasj[qb][j]);
            }
    __syncthreads();
    int nr = t >> 1, mh = t & 1;
    int n = n0 + nr, h = n >> 6, d = n & 63;
    int b_ = m0 >> 11;
    int s0 = (m0 & 2047) + mh * 64;
#pragma unroll
    for (int q = 0; q < 8; ++q) {
      us8 vdat = *(const us8*)&SMEM[nr * 136 + mh * 64 + q * 8];
      *(us8*)&outb[(((size_t)b_ * Hh + h) * HD + d) * Ss + s0 + q * 8] = vdat;
    }
  }
}

// Flash attention, causal, S^T = K Q^T, max-free exp2 softmax.  (R15, verified)
// grid 512 (64 bh x 8 p), 512 thr / 8 waves, 2 blocks/CU. Block p owns
// q-tiles {15-p, p}; wave w owns 16-row strip w*16 of each. KVBLK=64,
// double-buffered K/V, two-barrier counted-vmcnt pipeline:
// per tile {stage(kt+1); vmcnt(2); bar; asm-LDS compute; bar}.
// LDS elems: Ks b0 [0,4096) b1 [4096,8192); Vt b0 [8192,12288) b1 [12288,16384);
// Ps [16384,25600). 51200 B total.
__global__ __launch_bounds__(512, 2) void flash_attn(const unsigned short* __restrict__ qkv,
                                                     float* __restrict__ out) {
  const int id = blockIdx.x;
  const int bh = id & 63;
  const int p = id >> 6;            // 0..7
  const int b_ = bh >> 4, h = bh & 15;

  const unsigned short* qb  = qkv + (size_t)bh * (Ss * HD);
  const unsigned short* kb  = qkv + (size_t)(64 + bh) * (Ss * HD);
  const unsigned short* vtb = qkv + (size_t)(128 + bh) * (Ss * HD);  // [d][s]

  __shared__ __bf16 LDS[25600];        // 51200 B (see header comment)

  const int t = threadIdx.x;
  const int wave = t >> 6, lane = t & 63, quad = lane >> 4, ln = lane & 15;
  const int uw = wave >> 2;            // 64-row subtile half within each q-tile

  const int r6 = t >> 3;
  const int cstage = ((t & 7) ^ (r6 & 7)) * 8;
  const int t8 = t * 8;

  const int qts[2] = { 15 - p, p };    // big q-tile first; small reuses staging
  const int KTB = 2 * qts[0] + 2;      // 64-col K/V tiles (block-uniform)
  const int su0 = 2 * qts[0] + uw;
  const int su1 = 2 * qts[1] + uw;
  const int qrow0 = qts[0] * 128 + wave * 16 + ln;
  const int qrow1 = qts[1] * 128 + wave * 16 + ln;

  int ka0 = ln * 128 + ((quad ^ (ln & 7)) * 16);
  int ka1 = ln * 128 + (((4 + quad) ^ (ln & 7)) * 16);
  const int pw = (16384 + (wave * 16 + ln) * 72 + quad * 4) * 2;
  const int pr = (16384 + (wave * 16 + ln) * 72 + quad * 8) * 2;

  bf16x8 qf[2][2];                     // [qt][ks] — loaded BEFORE any gl_lds16
#pragma unroll
  for (int qt = 0; qt < 2; ++qt)
#pragma unroll
    for (int ks = 0; ks < 2; ++ks)
      qf[qt][ks] = *(const bf16x8*)(qb + (size_t)(qts[qt] * 128 + wave * 16 + ln) * HD +
                                    ks * 32 + quad * 8);

  bf16x8 onef;
#pragma unroll
  for (int j = 0; j < 8; ++j) onef[j] = (__bf16)1.0f;

  f32x4 o[2][4] = {};                  // [qt][g]
  f32x4 l4[2] = {};                    // [qt]

  auto body = [&](int kt) {
    if (kt > su0) return;              // fully masked for this wave
    const bool a1 = (kt <= su1);
    const int k0 = kt * 64;
    f32x4 s0[4] = {}, s1[4] = {};
    bf16x8 kf[2][2];

    DSR(kf[0][0], ka0, 0);    DSR(kf[1][0], ka0, 2048);
    DSR(kf[0][1], ka1, 0);    DSR(kf[1][1], ka1, 2048);
    LGKM0;
#pragma unroll
    for (int ks = 0; ks < 2; ++ks) {
      s0[0] = __builtin_amdgcn_mfma_f32_16x16x32_bf16(kf[0][ks], qf[0][ks], s0[0], 0, 0, 0);
      s0[1] = __builtin_amdgcn_mfma_f32_16x16x32_bf16(kf[1][ks], qf[0][ks], s0[1], 0, 0, 0);
    }
    if (a1)
#pragma unroll
      for (int ks = 0; ks < 2; ++ks) {
        s1[0] = __builtin_amdgcn_mfma_f32_16x16x32_bf16(kf[0][ks], qf[1][ks], s1[0], 0, 0, 0);
        s1[1] = __builtin_amdgcn_mfma_f32_16x16x32_bf16(kf[1][ks], qf[1][ks], s1[1], 0, 0, 0);
      }
    DSR(kf[0][0], ka0, 4096); DSR(kf[1][0], ka0, 6144);
    DSR(kf[0][1], ka1, 4096); DSR(kf[1][1], ka1, 6144);
    LGKM0;
#pragma unroll
    for (int ks = 0; ks < 2; ++ks) {
      s0[2] = __builtin_amdgcn_mfma_f32_16x16x32_bf16(kf[0][ks], qf[0][ks], s0[2], 0, 0, 0);
      s0[3] = __builtin_amdgcn_mfma_f32_16x16x32_bf16(kf[1][ks], qf[0][ks], s0[3], 0, 0, 0);
    }
    if (a1)
#pragma unroll
      for (int ks = 0; ks < 2; ++ks) {
        s1[2] = __builtin_amdgcn_mfma_f32_16x16x32_bf16(kf[0][ks], qf[1][ks], s1[2], 0, 0, 0);
        s1[3] = __builtin_amdgcn_mfma_f32_16x16x32_bf16(kf[1][ks], qf[1][ks], s1[3], 0, 0, 0);
      }

    if (kt == su0) {
#pragma unroll
      for (int g = 0; g < 4; ++g)
#pragma unroll
        for (int r = 0; r < 4; ++r) {
          int kcol = k0 + g * 16 + quad * 4 + r;
          if (kcol > qrow0) s0[g][r] = -__builtin_inff();
        }
    }
    {
      bf16x4 pk;
      pk = bf16x4{ (__bf16)EXP2(s0[0][0]), (__bf16)EXP2(s0[0][1]), (__bf16)EXP2(s0[0][2]), (__bf16)EXP2(s0[0][3]) };
      DSW(pw, pk, 0);
      pk = bf16x4{ (__bf16)EXP2(s0[1][0]), (__bf16)EXP2(s0[1][1]), (__bf16)EXP2(s0[1][2]), (__bf16)EXP2(s0[1][3]) };
      DSW(pw, pk, 32);
      pk = bf16x4{ (__bf16)EXP2(s0[2][0]), (__bf16)EXP2(s0[2][1]), (__bf16)EXP2(s0[2][2]), (__bf16)EXP2(s0[2][3]) };
      DSW(pw, pk, 64);
      pk = bf16x4{ (__bf16)EXP2(s0[3][0]), (__bf16)EXP2(s0[3][1]), (__bf16)EXP2(s0[3][2]), (__bf16)EXP2(s0[3][3]) };
      DSW(pw, pk, 96);
    }
    bf16x8 pf0[2], pf1[2];
    DSR(pf0[0], pr, 0); DSR(pf0[1], pr, 64);
    LGKM0;

    if (a1) {
      if (kt == su1) {
#pragma unroll
        for (int g = 0; g < 4; ++g)
#pragma unroll
          for (int r = 0; r < 4; ++r) {
            int kcol = k0 + g * 16 + quad * 4 + r;
            if (kcol > qrow1) s1[g][r] = -__builtin_inff();
          }
      }
      bf16x4 pk;
      pk = bf16x4{ (__bf16)EXP2(s1[0][0]), (__bf16)EXP2(s1[0][1]), (__bf16)EXP2(s1[0][2]), (__bf16)EXP2(s1[0][3]) };
      DSW(pw, pk, 0);
      pk = bf16x4{ (__bf16)EXP2(s1[1][0]), (__bf16)EXP2(s1[1][1]), (__bf16)EXP2(s1[1][2]), (__bf16)EXP2(s1[1][3]) };
      DSW(pw, pk, 32);
      pk = bf16x4{ (__bf16)EXP2(s1[2][0]), (__bf16)EXP2(s1[2][1]), (__bf16)EXP2(s1[2][2]), (__bf16)EXP2(s1[2][3]) };
      DSW(pw, pk, 64);
      pk = bf16x4{ (__bf16)EXP2(s1[3][0]), (__bf16)EXP2(s1[3][1]), (__bf16)EXP2(s1[3][2]), (__bf16)EXP2(s1[3][3]) };
      DSW(pw, pk, 96);
      DSR(pf1[0], pr, 0); DSR(pf1[1], pr, 64);
      LGKM0;
    }

    l4[0] = __builtin_amdgcn_mfma_f32_16x16x32_bf16(pf0[0], onef, l4[0], 0, 0, 0);
    l4[0] = __builtin_amdgcn_mfma_f32_16x16x32_bf16(pf0[1], onef, l4[0], 0, 0, 0);
    if (a1) {
      l4[1] = __builtin_amdgcn_mfma_f32_16x16x32_bf16(pf1[0], onef, l4[1], 0, 0, 0);
      l4[1] = __builtin_amdgcn_mfma_f32_16x16x32_bf16(pf1[1], onef, l4[1], 0, 0, 0);
    }

    DSR(kf[0][0], ka0, 16384); DSR(kf[1][0], ka0, 18432);
    DSR(kf[0][1], ka1, 16384); DSR(kf[1][1], ka1, 18432);
    LGKM0;
#pragma unroll
    for (int ks = 0; ks < 2; ++ks) {
      o[0][0] = __builtin_amdgcn_mfma_f32_16x16x32_bf16(pf0[ks], kf[0][ks], o[0][0], 0, 0, 0);
      o[0][1] = __builtin_amdgcn_mfma_f32_16x16x32_bf16(pf0[ks], kf[1][ks], o[0][1], 0, 0, 0);
    }
    if (a1)
#pragma unroll
      for (int ks = 0; ks < 2; ++ks) {
        o[1][0] = __builtin_amdgcn_mfma_f32_16x16x32_bf16(pf1[ks], kf[0][ks], o[1][0], 0, 0, 0);
        o[1][1] = __builtin_amdgcn_mfma_f32_16x16x32_bf16(pf1[ks], kf[1][ks], o[1][1], 0, 0, 0);
      }
    DSR(kf[0][0], ka0, 20480); DSR(kf[1][0], ka0, 22528);
    DSR(kf[0][1], ka1, 20480); DSR(kf[1][1], ka1, 22528);
    LGKM0;
#pragma unroll
    for (int ks = 0; ks < 2; ++ks) {
      o[0][2] = __builtin_amdgcn_mfma_f32_16x16x32_bf16(pf0[ks], kf[0][ks], o[0][2], 0, 0, 0);
      o[0][3] = __builtin_amdgcn_mfma_f32_16x16x32_bf16(pf0[ks], kf[1][ks], o[0][3], 0, 0, 0);
    }
    if (a1)
#pragma unroll
      for (int ks = 0; ks < 2; ++ks) {
        o[1][2] = __builtin_amdgcn_mfma_f32_16x16x32_bf16(pf1[ks], kf[0][ks], o[1][2], 0, 0, 0);
        o[1][3] = __builtin_amdgcn_mfma_f32_16x16x32_bf16(pf1[ks], kf[1][ks], o[1][3], 0, 0, 0);
      }
  };

  // ---- prologue: stage tile 0 -> buf0
  gl_lds16(kb + r6 * HD + cstage,  &LDS[t8]);
  gl_lds16(vtb + r6 * Ss + cstage, &LDS[8192 + t8]);

#pragma unroll 1
  for (int kt = 0; kt < KTB - 1; ++kt) {
    const int sb = (kt & 1) ^ 1;       // stage buffer for tile kt+1
    gl_lds16(kb + (size_t)(kt + 1) * (64 * HD) + r6 * HD + cstage, &LDS[sb * 4096 + t8]);
    gl_lds16(vtb + (kt + 1) * 64 + r6 * Ss + cstage,               &LDS[8192 + sb * 4096 + t8]);
    asm volatile("s_waitcnt vmcnt(2)" ::: "memory");   // tile kt's K,V arrived
    asm volatile("s_barrier" ::: "memory");
    body(kt);
    asm volatile("s_barrier" ::: "memory");            // all reads done before next stage
    ka0 ^= 8192; ka1 ^= 8192;
  }
  asm volatile("s_waitcnt vmcnt(0)" ::: "memory");
  asm volatile("s_barrier" ::: "memory");
  body(KTB - 1);

  // epilogue: both q-tiles
#pragma unroll
  for (int qt = 0; qt < 2; ++qt) {
    float linv[4];
#pragma unroll
    for (int r = 0; r < 4; ++r) linv[r] = 1.0f / l4[qt][r];
#pragma unroll
    for (int g = 0; g < 4; ++g)
#pragma unroll
      for (int r = 0; r < 4; ++r) {
        int orow = qts[qt] * 128 + wave * 16 + quad * 4 + r;
        out[((size_t)b_ * Ss + orow) * Ee + h * HD + g * 16 + ln] = o[qt][g][r] * linv[r];
      }
  }
}

extern "C" void kernel_launch(void* const* d_in, const int* in_sizes, int n_in,
                              void* d_out, int out_size, void* d_ws, size_t ws_size,
                              hipStream_t stream) {
  const float* x  = (const float*)d_in[0];
  const float* Wq = (const float*)d_in[1];
  const float* bq = (const float*)d_in[2];
  const float* Wk = (const float*)d_in[3];
  const float* bk = (const float*)d_in[4];
  const float* Wv = (const float*)d_in[5];
  const float* bv = (const float*)d_in[6];
  float* out = (float*)d_out;

  unsigned short* ws  = (unsigned short*)d_ws;
  unsigned short* xb  = ws;                                   // 8388608
  unsigned short* wb  = ws + 8388608;                         // 3 * 1048576
  unsigned short* qkv = ws + 8388608 + 3 * 1048576;           // 3 * 8388608

  cvt_all<<<11264, 256, 0, stream>>>(x, Wq, Wk, Wv, xb, wb);
  qkv_gemm<<<dim3(64, 8, 3), 256, 0, stream>>>(xb, wb, bq, bk, bv, qkv);
  flash_attn<<<512, 512, 0, stream>>>(qkv, out);
}